// Round 7
// baseline (96.662 us; speedup 1.0000x reference)
//
#include <hip/hip_runtime.h>

#define Bb 64
#define Ll 32
#define Hh 128
#define Oo 16384
#define Cc 32
#define TOo 64
#define NT 512

// ws layout (floats): A[8192] | SA2w[64] | w2h[128] | w1t[4096] | gcoef[256]

// ---------------------------------------------------------------------------
// prep: A = relu(z@Wz+bz)@W1[:H];  SA2w[b] = sum 0.5*W2*A[b,:] + b2
// side: w1t = W1_f^T (h-major), w2h = 0.5*W2, gcoef[h] = {w1b[h], b1[h]}
// ---------------------------------------------------------------------------
__global__ __launch_bounds__(256) void prep_kernel(
    const float* __restrict__ z, const float* __restrict__ Wz,
    const float* __restrict__ bz, const float* __restrict__ W1,
    const float* __restrict__ b1, const float* __restrict__ W2,
    const float* __restrict__ b2,
    float* __restrict__ A, float* __restrict__ SA2w,
    float* __restrict__ w2h, float* __restrict__ w1t,
    float* __restrict__ gcoef)
{
    __shared__ float pz[2][Hh];
    __shared__ float ps[2][Hh];
    const int t  = threadIdx.x;
    const int h  = t & (Hh - 1);
    const int bb = t >> 7;
    const int b  = blockIdx.x * 2 + bb;

    float v = bz[h];
#pragma unroll
    for (int c = 0; c < Ll; ++c)
        v = fmaf(z[b * Ll + c], Wz[c * Hh + h], v);
    pz[bb][h] = fmaxf(v, 0.f);
    __syncthreads();

    float a = 0.f;
#pragma unroll
    for (int k = 0; k < Hh; ++k)
        a = fmaf(pz[bb][k], W1[k * Hh + h], a);
    A[b * Hh + h] = a;
    ps[bb][h] = 0.5f * W2[h] * a;
    __syncthreads();

    if (h == 0) {
        float s = b2[0];
        for (int k = 0; k < Hh; ++k) s += ps[bb][k];
        SA2w[b] = s;
    }

    // side work (each of 32 blocks handles 4 h-columns)
    if (t < 128) {
        const int h2 = blockIdx.x * 4 + (t >> 5);
        const int c  = t & 31;
        w1t[h2 * Cc + c] = W1[(Hh + c) * Hh + h2];
    }
    if (t < 4) {
        const int h2 = blockIdx.x * 4 + t;
        w2h[h2] = 0.5f * W2[h2];
        gcoef[2 * h2 + 0] = W1[(Hh + Cc) * Hh + h2];
        gcoef[2 * h2 + 1] = b1[h2];
    }
}

// ---------------------------------------------------------------------------
// main: out[b,o] = SA2w[b] + sum_h w2h[h]*g[o,h] + sum_h w2h[h]*|A[b,h]+g[o,h]|
//   (w*relu(x) = 0.5*w*x + 0.5*w*|x|, exact; b2 folded into SA2w)
// 512 thr = 8 waves; lane = o (coalesced); wave owns 8 b-rows, full h.
// COMPACT ROLLED LOOPS (I-cache resident). A/w2 via uniform s_load (scalar
// pipe), g via conflict-free stride-65 ds_read_b32.
// ---------------------------------------------------------------------------
__global__ __launch_bounds__(NT) void main_kernel(
    const float* __restrict__ A,   const float* __restrict__ SA2w,
    const float* __restrict__ fe,  const float* __restrict__ fb,
    const float* __restrict__ w2h, const float* __restrict__ w1t,
    const float* __restrict__ gcoef, float* __restrict__ out)
{
    __shared__ __align__(16) float fe_s[TOo][36];   // 9 KB (36: aligned+rotated)
    __shared__ float g_s[Hh][TOo + 1];              // 33.3 KB, stride-65

    const int t    = threadIdx.x;
    const int o0   = blockIdx.x * TOo;
    const int lane = t & 63;
    const int wave = __builtin_amdgcn_readfirstlane(t >> 6);  // uniform 0..7

    // stage fe tile: coalesced global read, strided LDS write
    {
        const float4 f4 = ((const float4*)(fe + o0 * Cc))[t];
        *(float4*)&fe_s[t >> 3][(t & 7) << 2] = f4;
    }
    __syncthreads();

    // per-lane fe row -> 32 VGPRs (dead after G phase)
    float4 fer[8];
#pragma unroll
    for (int k = 0; k < 8; ++k)
        fer[k] = *(const float4*)&fe_s[lane][4 * k];
    const float fbv = fb[o0 + lane];

    // --- G phase: wave's h-slice [16*wave, 16*wave+16), rolled ---
    const int h0 = wave * 16;
#pragma unroll 1
    for (int j = 0; j < 16; ++j) {
        const int h = h0 + j;
        const float w1b = gcoef[2 * h + 0];          // uniform -> s_load
        const float b1h = gcoef[2 * h + 1];
        const float* __restrict__ wt = w1t + h * Cc; // uniform -> s_load
        float g = fmaf(fbv, w1b, b1h);
#pragma unroll
        for (int k = 0; k < 8; ++k) {
            g = fmaf(fer[k].x, wt[4 * k + 0], g);
            g = fmaf(fer[k].y, wt[4 * k + 1], g);
            g = fmaf(fer[k].z, wt[4 * k + 2], g);
            g = fmaf(fer[k].w, wt[4 * k + 3], g);
        }
        g_s[h][lane] = g;    // (h+lane)%32 rotation: conflict-free
    }
    __syncthreads();

    // --- main loop: 8 iters x (16 h, 8 b), rolled ---
    const int b0 = wave * 8;
    float acc[8];
#pragma unroll
    for (int bi = 0; bi < 8; ++bi) acc[bi] = 0.f;
    float sg = 0.f;

#pragma unroll 1
    for (int tt = 0; tt < 8; ++tt) {
        float gj[16];
#pragma unroll
        for (int jr = 0; jr < 16; ++jr)
            gj[jr] = g_s[16 * tt + jr][lane];        // stride-65: conflict-free
        const float* __restrict__ wp = w2h + 16 * tt;  // uniform
        float w[16];
#pragma unroll
        for (int jr = 0; jr < 16; ++jr) w[jr] = wp[jr];  // s_load_dwordx16
#pragma unroll
        for (int jr = 0; jr < 16; ++jr)
            sg = fmaf(w[jr], gj[jr], sg);
#pragma unroll
        for (int bi = 0; bi < 8; ++bi) {
            const float* __restrict__ Ap = A + (b0 + bi) * Hh + 16 * tt; // uniform
#pragma unroll
            for (int jr = 0; jr < 16; ++jr)
                acc[bi] = fmaf(__builtin_fabsf(gj[jr] + Ap[jr]), w[jr], acc[bi]);
        }
    }

    // --- epilogue: coalesced row stores ---
#pragma unroll
    for (int bi = 0; bi < 8; ++bi) {
        const int b = b0 + bi;
        out[b * Oo + o0 + lane] = acc[bi] + sg + SA2w[b];  // SA2w: s_load
    }
}

extern "C" void kernel_launch(void* const* d_in, const int* in_sizes, int n_in,
                              void* d_out, int out_size, void* d_ws, size_t ws_size,
                              hipStream_t stream) {
    (void)in_sizes; (void)n_in; (void)out_size; (void)ws_size;
    const float* z   = (const float*)d_in[0];   // (64,32)
    const float* fe  = (const float*)d_in[1];   // (16384,32)
    const float* fb  = (const float*)d_in[2];   // (16384,1)
    const float* Wz  = (const float*)d_in[3];   // (32,128)
    const float* bz  = (const float*)d_in[4];   // (128,)
    const float* W1  = (const float*)d_in[5];   // (161,128)
    const float* b1  = (const float*)d_in[6];   // (128,)
    const float* W2  = (const float*)d_in[7];   // (128,1)
    const float* b2  = (const float*)d_in[8];   // (1,)
    float* out   = (float*)d_out;               // (64,16384)
    float* A     = (float*)d_ws;                // 8192
    float* SA2w  = A + Bb * Hh;                 // 64
    float* w2h   = SA2w + Bb;                   // 128
    float* w1t   = w2h + Hh;                    // 4096
    float* gcoef = w1t + Hh * Cc;               // 256

    prep_kernel<<<Bb / 2, 256, 0, stream>>>(z, Wz, bz, W1, b1, W2, b2,
                                            A, SA2w, w2h, w1t, gcoef);
    main_kernel<<<Oo / TOo, NT, 0, stream>>>(A, SA2w, fe, fb, w2h, w1t,
                                             gcoef, out);
}